// Round 5
// baseline (358.410 us; speedup 1.0000x reference)
//
#include <hip/hip_runtime.h>
#include <math.h>

#define EPS 1e-5f
#define NPK (4096 * 128)   // 524288 pixels
#define HSTR 72            // LDS row stride in shorts (pad: 144 B = 36 dwords)

typedef __attribute__((ext_vector_type(8))) short bf16x8;   // 8 bf16 = 4 VGPRs
typedef __attribute__((ext_vector_type(4))) float f32x4;

__device__ __forceinline__ short f2bf(float f) {
    union { float f; unsigned u; } x; x.f = f;
    unsigned r = x.u + 0x7fffu + ((x.u >> 16) & 1u);   // round-to-nearest-even
    return (short)(r >> 16);
}

// ws layout (floats): A1[192] C1[64] C2[64] C3[128] | bf16: W2frag[4096] W3frag[8192]
// WNfrag = BN-folded weights pre-swizzled into MFMA B-fragment per-lane order:
//   frag[((nt*2+ks)*64 + lane)*8 + j] = Wfold[o = nt*16 + (lane&15)][i = ks*32 + (lane>>4)*8 + j]
#define WS_A1 0
#define WS_C1 192
#define WS_C2 256
#define WS_C3 320
#define WS_BF 448

__global__ void prep_kernel(
    const float* __restrict__ W1, const float* __restrict__ b1,
    const float* __restrict__ g1, const float* __restrict__ be1,
    const float* __restrict__ m1, const float* __restrict__ v1,
    const float* __restrict__ W2, const float* __restrict__ b2,
    const float* __restrict__ g2, const float* __restrict__ be2,
    const float* __restrict__ m2, const float* __restrict__ v2,
    const float* __restrict__ W3, const float* __restrict__ b3,
    const float* __restrict__ g3, const float* __restrict__ be3,
    const float* __restrict__ m3, const float* __restrict__ v3,
    float* __restrict__ ws)
{
    const int t = blockIdx.x * 256 + threadIdx.x;
    const int stride = gridDim.x * 256;
    if (t < 64) {
        float inv1 = g1[t] * rsqrtf(v1[t] + EPS);
        ws[WS_C1 + t] = b1[t] * inv1 + be1[t] - m1[t] * inv1;
        ws[WS_A1 + t * 3 + 0] = W1[t * 3 + 0] * inv1;
        ws[WS_A1 + t * 3 + 1] = W1[t * 3 + 1] * inv1;
        ws[WS_A1 + t * 3 + 2] = W1[t * 3 + 2] * inv1;
        float inv2 = g2[t] * rsqrtf(v2[t] + EPS);
        ws[WS_C2 + t] = b2[t] * inv2 + be2[t] - m2[t] * inv2;
    }
    if (t >= 128 && t < 256) {
        int o = t - 128;
        float inv3 = g3[o] * rsqrtf(v3[o] + EPS);
        ws[WS_C3 + o] = b3[o] * inv3 + be3[o] - m3[o] * inv3;
    }
    short* W2f = (short*)(ws + WS_BF);
    short* W3f = W2f + 64 * 64;
    for (int idx = t; idx < 64 * 64; idx += stride) {
        int j = idx & 7, lane = (idx >> 3) & 63, tile = idx >> 9;
        int nt = tile >> 1, ks = tile & 1;
        int o = nt * 16 + (lane & 15);
        int i = ks * 32 + (lane >> 4) * 8 + j;
        float inv = g2[o] * rsqrtf(v2[o] + EPS);
        W2f[idx] = f2bf(W2[o * 64 + i] * inv);
    }
    for (int idx = t; idx < 128 * 64; idx += stride) {
        int j = idx & 7, lane = (idx >> 3) & 63, tile = idx >> 9;
        int nt = tile >> 1, ks = tile & 1;
        int o = nt * 16 + (lane & 15);
        int i = ks * 32 + (lane >> 4) * 8 + j;
        float inv = g3[o] * rsqrtf(v3[o] + EPS);
        W3f[idx] = f2bf(W3[o * 64 + i] * inv);
    }
}

// BARRIER-FREE design: each wave owns 32 pixels end-to-end. L1 computes exactly
// the rows this wave's MFMAs consume; DS ops are in-order within a wave, so
// ds_write -> ds_read needs no __syncthreads. h1's A-fragments are register-
// resident before h2 overwrites the same LDS rows (single 18.4 KB buffer ->
// 8 blocks/CU). No barrier => no vmcnt(0) drains => stores stream continuously.
// M = pixels, N = channels: C/D layout (col=lane&15=channel, row=quad*4+reg=pixel)
// gives each lane 4 consecutive pixels of one channel => plain f32x4 stores.
__global__ __launch_bounds__(256) void pointnet_mfma(
    const float* __restrict__ x, const float* __restrict__ valid,
    const float* __restrict__ ws, float* __restrict__ out)
{
    __shared__ short h[128 * HSTR];   // 18432 B, one buffer reused h1 -> h2

    const int t = threadIdx.x;
    const int lane = t & 63;
    const int w = t >> 6;
    const int lanelo = lane & 15;
    const int quad = lane >> 4;
    const int pbase = blockIdx.x * 128 + w * 32;       // this wave's 32 pixels
    short* __restrict__ hw = &h[(w * 32) * HSTR];      // wave-private 32 rows

    const float* __restrict__ A1 = ws + WS_A1;
    const float* __restrict__ C1 = ws + WS_C1;
    const float* __restrict__ C2 = ws + WS_C2;
    const float* __restrict__ C3 = ws + WS_C3;
    const short* __restrict__ W2f = (const short*)(ws + WS_BF);
    const short* __restrict__ W3f = W2f + 64 * 64;

    // ---- Layer 1: 3 -> 64 fp32. Two lanes per pixel, 32 channels each. ----
    {
        const int pl = lane & 31;
        const int half = lane >> 5;
        const int pg = pbase + pl;
        const float x0 = x[pg];
        const float x1 = x[pg + NPK];
        const float x2 = x[pg + 2 * NPK];
        const int cb = half * 32;
#pragma unroll
        for (int g = 0; g < 4; ++g) {
            bf16x8 vb;
#pragma unroll
            for (int j = 0; j < 8; ++j) {
                const int ch = cb + g * 8 + j;
                float a = C1[ch];
                a = fmaf(A1[ch * 3 + 0], x0, a);
                a = fmaf(A1[ch * 3 + 1], x1, a);
                a = fmaf(A1[ch * 3 + 2], x2, a);
                vb[j] = f2bf(fmaxf(a, 0.0f));
            }
            *(bf16x8*)&hw[pl * HSTR + cb + g * 8] = vb;
        }
    }

    // h1 A-fragments -> registers (in-order DS: sees the writes above)
    bf16x8 a1f[2][2];
#pragma unroll
    for (int mt = 0; mt < 2; ++mt)
#pragma unroll
        for (int ks = 0; ks < 2; ++ks)
            a1f[mt][ks] = *(const bf16x8*)&hw[(mt * 16 + lanelo) * HSTR + ks * 32 + quad * 8];

    // ---- Layer 2: 2 m-tiles x 4 n-tiles, K=64; h2 written over h1 rows ----
#pragma unroll
    for (int nt = 0; nt < 4; ++nt) {
        bf16x8 b0 = *(const bf16x8*)&W2f[((nt * 2 + 0) * 64 + lane) * 8];
        bf16x8 b1 = *(const bf16x8*)&W2f[((nt * 2 + 1) * 64 + lane) * 8];
        const float bias = C2[nt * 16 + lanelo];
#pragma unroll
        for (int mt = 0; mt < 2; ++mt) {
            f32x4 acc = {0.f, 0.f, 0.f, 0.f};
            acc = __builtin_amdgcn_mfma_f32_16x16x32_bf16(a1f[mt][0], b0, acc, 0, 0, 0);
            acc = __builtin_amdgcn_mfma_f32_16x16x32_bf16(a1f[mt][1], b1, acc, 0, 0, 0);
#pragma unroll
            for (int r = 0; r < 4; ++r)
                hw[(mt * 16 + quad * 4 + r) * HSTR + nt * 16 + lanelo] =
                    f2bf(fmaxf(acc[r] + bias, 0.0f));
        }
    }

    // h2 A-fragments -> registers
    bf16x8 a2f[2][2];
#pragma unroll
    for (int mt = 0; mt < 2; ++mt)
#pragma unroll
        for (int ks = 0; ks < 2; ++ks)
            a2f[mt][ks] = *(const bf16x8*)&hw[(mt * 16 + lanelo) * HSTR + ks * 32 + quad * 8];

    // valid mask straight from global (L1/L2 broadcast), no LDS
    f32x4 vv[2];
    vv[0] = *(const f32x4*)&valid[pbase + quad * 4];
    vv[1] = *(const f32x4*)&valid[pbase + 16 + quad * 4];

    // ---- Layer 3: 2 m-tiles x 8 n-tiles, K=64; fused epilogue ----
#pragma unroll
    for (int nt = 0; nt < 8; ++nt) {
        bf16x8 b0 = *(const bf16x8*)&W3f[((nt * 2 + 0) * 64 + lane) * 8];
        bf16x8 b1 = *(const bf16x8*)&W3f[((nt * 2 + 1) * 64 + lane) * 8];
        const float bias = C3[nt * 16 + lanelo];
        float* __restrict__ outc = out + (long)(nt * 16 + lanelo) * NPK + pbase;
#pragma unroll
        for (int mt = 0; mt < 2; ++mt) {
            f32x4 acc = {0.f, 0.f, 0.f, 0.f};
            acc = __builtin_amdgcn_mfma_f32_16x16x32_bf16(a2f[mt][0], b0, acc, 0, 0, 0);
            acc = __builtin_amdgcn_mfma_f32_16x16x32_bf16(a2f[mt][1], b1, acc, 0, 0, 0);
            f32x4 o;
#pragma unroll
            for (int r = 0; r < 4; ++r)
                o[r] = fmaxf(acc[r] + bias, 0.0f) * vv[mt][r];
            *(f32x4*)&outc[mt * 16 + quad * 4] = o;
        }
    }
}

extern "C" void kernel_launch(void* const* d_in, const int* in_sizes, int n_in,
                              void* d_out, int out_size, void* d_ws, size_t ws_size,
                              hipStream_t stream) {
    const float* x     = (const float*)d_in[0];
    const float* valid = (const float*)d_in[1];

    const float* W1 = (const float*)d_in[2];
    const float* b1 = (const float*)d_in[3];
    const float* g1 = (const float*)d_in[4];
    const float* be1 = (const float*)d_in[5];
    const float* m1 = (const float*)d_in[6];
    const float* v1 = (const float*)d_in[7];

    const float* W2 = (const float*)d_in[8];
    const float* b2 = (const float*)d_in[9];
    const float* g2 = (const float*)d_in[10];
    const float* be2 = (const float*)d_in[11];
    const float* m2 = (const float*)d_in[12];
    const float* v2 = (const float*)d_in[13];

    const float* W3 = (const float*)d_in[14];
    const float* b3 = (const float*)d_in[15];
    const float* g3 = (const float*)d_in[16];
    const float* be3 = (const float*)d_in[17];
    const float* m3 = (const float*)d_in[18];
    const float* v3 = (const float*)d_in[19];

    float* ws  = (float*)d_ws;
    float* out = (float*)d_out;

    prep_kernel<<<16, 256, 0, stream>>>(W1, b1, g1, be1, m1, v1,
                                        W2, b2, g2, be2, m2, v2,
                                        W3, b3, g3, be3, m3, v3, ws);

    pointnet_mfma<<<NPK / 128, 256, 0, stream>>>(x, valid, ws, out);
}